// Round 9
// baseline (2035.730 us; speedup 1.0000x reference)
//
#include <hip/hip_runtime.h>

// B=64, T=50, ROWS=COLS=64, RES=0.03, H_FULL=W_FULL=256
// flat = 14*14*32 = 6272, stored TRANSPOSED: wsFlatT[k][b]
// out: (64,51,6) float32
//
// 101 graph nodes: TC0 D0 TC1 D1 ... TC49 D49 TC50
//  k_tc(st):   [tail of step st-1, computed redundantly by all 8 oct-WGs of batch b:
//               h1 = relu(b0 + sum_ks wsPart + W0 rows(s_{st-1},a_{st-1}));
//               h2 = relu(W1 h1 + b1) (k-outer, coalesced w1d reads);
//               ds = W2^T h2 + b2; s_st = s_{st-1} + ds  (bit-identical across octs)]
//              + oct0 writes out row st + wsS; then params + conv stack -> wsFlatT[k][b].
//              st==50: tail only. 512 WGs = (b, oct), 256 thr, 2 WGs/CU.
//  k_dense0:   flat-part K-split GEMM -> wsPart[b][32][256] (b-major).
// State double-buffered by parity: read wsS[(st-1)&1], write wsS[st&1].

// ---------------- k_tc ----------------
__global__ __launch_bounds__(256, 2)
void k_tc(const float* __restrict__ action, const float* __restrict__ state,
          const float* __restrict__ res, const float* __restrict__ env,
          const float* __restrict__ origin,
          const float* __restrict__ w1, const float* __restrict__ b1,
          const float* __restrict__ w2, const float* __restrict__ b2,
          const float* __restrict__ w0, const float* __restrict__ b0,
          const float* __restrict__ w1d, const float* __restrict__ b1d,
          const float* __restrict__ w2d, const float* __restrict__ b2d,
          const float* __restrict__ wsPart, float* __restrict__ wsS,
          float* __restrict__ wsFlatT, float* __restrict__ out, int st)
{
    const int wg  = blockIdx.x;
    const int b   = wg >> 3;
    const int oct = wg & 7;
    const int tid = threadIdx.x;

    __shared__ float w1l[864];
    __shared__ float w2l[4608];
    __shared__ float b2l[32];
    __shared__ float bAl[16];
    __shared__ float sSl[8];
    __shared__ int   prm[12];
    __shared__ float h1l[256];
    __shared__ float wred[24];
    __shared__ float pool1s[6*31*20];     // 14880 B
    __shared__ unsigned char inl[14*64];  // 896 B

    // ---- conv weight staging issued first (long latency-to-use) ----
    if (st < 50){
        for (int i = tid; i < 216; i += 256)
            *(float4*)&w1l[i*4] = *(const float4*)(w1 + i*4);
        for (int i = tid; i < 1152; i += 256)
            *(float4*)&w2l[i*4] = *(const float4*)(w2 + i*4);
        if (tid < 32) b2l[tid] = b2[tid];
    }

    // ---- tail: compute s_st (redundant per oct; bit-identical) ----
    if (st == 0){
        if (tid < 6) sSl[tid] = state[b*306 + tid];
        __syncthreads();
    } else {
        const float* sp = wsS + ((st-1)&1)*512 + b*8;
        const float a0p = action[b*100 + (st-1)*2 + 0];
        const float a1p = action[b*100 + (st-1)*2 + 1];
        const int col = tid;

        // h1 column per thread: coalesced wsPart (b-major) + W0 state/action rows
        float hacc = b0[col];
        #pragma unroll
        for (int j = 0; j < 6; j++) hacc = fmaf(sp[j], w0[j*256 + col], hacc);
        hacc = fmaf(a0p, w0[1536 + col], hacc);
        hacc = fmaf(a1p, w0[1792 + col], hacc);
        {
            const float* pp = wsPart + b*8192 + col;
            float e0 = 0.f, e1 = 0.f;
            #pragma unroll
            for (int ks = 0; ks < 32; ks += 2){
                e0 += pp[ks*256];
                e1 += pp[(ks+1)*256];
            }
            hacc += e0 + e1;
        }
        h1l[col] = fmaxf(hacc, 0.f);
        __syncthreads();

        // dense1 column per thread, k-outer (coalesced scalar w1d reads), 2 chains
        float d0 = b1d[col], d1 = 0.f;
        const float* wc = w1d + col;
        #pragma unroll 8
        for (int k = 0; k < 256; k += 2){
            d0 = fmaf(h1l[k],   wc[k*256],     d0);
            d1 = fmaf(h1l[k+1], wc[(k+1)*256], d1);
        }
        float h2 = fmaxf(d0 + d1, 0.f);

        // dense2 partials + wave reduce (4 waves)
        float p[6];
        const float* wr = w2d + col*6;
        #pragma unroll
        for (int j = 0; j < 6; j++) p[j] = h2 * wr[j];
        #pragma unroll
        for (int off = 32; off > 0; off >>= 1){
            #pragma unroll
            for (int j = 0; j < 6; j++) p[j] += __shfl_down(p[j], off, 64);
        }
        if ((tid & 63) == 0){
            #pragma unroll
            for (int j = 0; j < 6; j++) wred[(tid >> 6)*6 + j] = p[j];
        }
        __syncthreads();
        if (tid < 6){
            float ds = wred[tid] + wred[6+tid] + wred[12+tid] + wred[18+tid] + b2d[tid];
            sSl[tid] = sp[tid] + ds;
        }
        __syncthreads();
    }

    if (oct == 0 && tid < 6){
        out[b*306 + st*6 + tid] = sSl[tid];
        wsS[(st & 1)*512 + b*8 + tid] = sSl[tid];
    }
    if (st >= 50) return;

    // ---- params + conv constants ----
    if (tid == 0){
        float org0 = origin[2*b], org1 = origin[2*b+1];
        int ccol = (int)(sSl[4] / 0.03f + org1);   // trunc == astype(int32)
        int crow = (int)(sSl[5] / 0.03f + org0);
        float res0 = res[b*50];
        float lo0 = org0 - (float)crow + 32.0f;
        float lo1 = org1 - (float)ccol + 32.0f;
        prm[0] = crow; prm[1] = ccol;
        #pragma unroll
        for (int p = 0; p < 3; p++){
            int rr = (int)(sSl[2*p+1]/res0 + lo0);
            int cc = (int)(sSl[2*p  ]/res0 + lo1);
            prm[2+p] = rr; prm[5+p] = cc;
            prm[8+p] = (rr>=0 && rr<64 && cc>=0 && cc<64) ? 1 : 0;
        }
    }
    if (tid < 16){
        float s4 = 0.f, s5 = 0.f;
        #pragma unroll
        for (int k = 0; k < 9; k++){
            s4 += w1[(k*6 + 4)*16 + tid];
            s5 += w1[(k*6 + 5)*16 + tid];
        }
        float a0 = action[b*100 + st*2 + 0];
        float a1 = action[b*100 + st*2 + 1];
        bAl[tid] = b1[tid] + a0*s4 + a1*s5;
    }
    __syncthreads();

    // ---- conv geometry for this oct (pool2 rows 2,2,2,2,2,2,1,1) ----
    const int p2lo = (oct < 6) ? 2*oct : 12 + (oct - 6);
    const int p2n  = (oct < 6) ? 2 : 1;
    const int p1n  = 2*p2n + 2;      // 6 or 4
    const int p1lo = 2*p2lo;
    const int ilo  = 4*p2lo;
    const int inn  = 2*p1n + 2;      // 14 or 10

    // window gather
    {
        const int crow = prm[0], ccol = prm[1];
        for (int idx = tid; idx < inn*64; idx += 256){
            int i = idx >> 6, j = idx & 63;
            int r = crow - 32 + ilo + i;
            int c = ccol - 32 + j;
            float v = (r>=0 && r<256 && c>=0 && c<256) ? env[b*65536 + (r<<8) + c] : 0.f;
            inl[idx] = (unsigned char)v;
        }
    }
    __syncthreads();

    // conv1 + pool1
    {
        int pr[3], pc[3], pvld[3];
        #pragma unroll
        for (int p = 0; p < 3; p++){ pr[p]=prm[2+p]; pc[p]=prm[5+p]; pvld[p]=prm[8+p]; }

        for (int u = tid; u < p1n*31; u += 256){
            int pl = u / 31;
            int j  = u - pl*31;
            float l[4][4];
            #pragma unroll
            for (int dy = 0; dy < 4; dy++)
                #pragma unroll
                for (int dx = 0; dx < 4; dx++)
                    l[dy][dx] = (float)inl[(2*pl + dy)*64 + 2*j + dx];

            float m[16];
            #pragma unroll
            for (int o = 0; o < 16; o++) m[o] = 0.f;   // relu>=0

            #pragma unroll
            for (int dy = 0; dy < 2; dy++){
                #pragma unroll
                for (int dx = 0; dx < 2; dx++){
                    int rg = 2*(p1lo + pl) + dy;
                    int cg = 2*j + dx;
                    bool pf[3]; int pidx[3];
                    #pragma unroll
                    for (int p = 0; p < 3; p++){
                        int kr = pr[p] - rg, kc = pc[p] - cg;
                        pf[p] = pvld[p] && kr >= 0 && kr < 3 && kc >= 0 && kc < 3;
                        pidx[p] = pf[p] ? ((kr*3 + kc)*6 + p)*16 : 0;
                    }
                    #pragma unroll
                    for (int o = 0; o < 16; o++){
                        float v = bAl[o];
                        #pragma unroll
                        for (int kr = 0; kr < 3; kr++)
                            #pragma unroll
                            for (int kc = 0; kc < 3; kc++)
                                v = fmaf(l[dy+kr][dx+kc], w1l[((kr*3 + kc)*6 + 3)*16 + o], v);
                        if (pf[0]) v += w1l[pidx[0] + o];
                        if (pf[1]) v += w1l[pidx[1] + o];
                        if (pf[2]) v += w1l[pidx[2] + o];
                        v = fmaxf(v, 0.f);
                        m[o] = fmaxf(m[o], v);
                    }
                }
            }
            float* pd = &pool1s[(pl*31 + j)*20];
            *(float4*)(pd     ) = make_float4(m[0],  m[1],  m[2],  m[3]);
            *(float4*)(pd + 4 ) = make_float4(m[4],  m[5],  m[6],  m[7]);
            *(float4*)(pd + 8 ) = make_float4(m[8],  m[9],  m[10], m[11]);
            *(float4*)(pd + 12) = make_float4(m[12], m[13], m[14], m[15]);
        }
    }
    __syncthreads();

    // conv2 + pool2 -> wsFlatT[k][b] (transposed scatter stores)
    for (int u = tid; u < p2n*14*8; u += 256){
        int pi  = u / 112;
        int rem = u - pi*112;
        int jj  = rem >> 3;
        int oq  = rem & 7;
        int o0  = oq*4;

        float acc[4][4];
        #pragma unroll
        for (int ps = 0; ps < 4; ps++)
            #pragma unroll
            for (int c = 0; c < 4; c++) acc[ps][c] = 0.f;

        #pragma unroll 1
        for (int t9 = 0; t9 < 9; t9++){
            int kr = t9 / 3, kc = t9 - 3*(t9/3);
            const float* pb = &pool1s[((2*pi + kr)*31 + (2*jj + kc))*20];
            const float* wb = &w2l[(kr*3 + kc)*512 + o0];
            #pragma unroll
            for (int kib = 0; kib < 4; kib++){
                float4 q00 = *(const float4*)(pb + kib*4);
                float4 q01 = *(const float4*)(pb + 20 + kib*4);
                float4 q10 = *(const float4*)(pb + 620 + kib*4);
                float4 q11 = *(const float4*)(pb + 640 + kib*4);
                float pq[4][4] = {
                    {q00.x, q00.y, q00.z, q00.w},
                    {q01.x, q01.y, q01.z, q01.w},
                    {q10.x, q10.y, q10.z, q10.w},
                    {q11.x, q11.y, q11.z, q11.w}};
                #pragma unroll
                for (int kk = 0; kk < 4; kk++){
                    float4 wv = *(const float4*)(wb + (kib*4 + kk)*32);
                    #pragma unroll
                    for (int ps = 0; ps < 4; ps++){
                        float pvv = pq[ps][kk];
                        acc[ps][0] = fmaf(pvv, wv.x, acc[ps][0]);
                        acc[ps][1] = fmaf(pvv, wv.y, acc[ps][1]);
                        acc[ps][2] = fmaf(pvv, wv.z, acc[ps][2]);
                        acc[ps][3] = fmaf(pvv, wv.w, acc[ps][3]);
                    }
                }
            }
        }
        int kb = ((p2lo + pi)*14 + jj)*32 + o0;
        #pragma unroll
        for (int c = 0; c < 4; c++){
            float bb = b2l[o0 + c];
            float v0 = fmaxf(acc[0][c] + bb, 0.f);
            float v1 = fmaxf(acc[1][c] + bb, 0.f);
            float v2 = fmaxf(acc[2][c] + bb, 0.f);
            float v3 = fmaxf(acc[3][c] + bb, 0.f);
            wsFlatT[(kb + c)*64 + b] = fmaxf(fmaxf(v0, v1), fmaxf(v2, v3));
        }
    }
}

// ---------------- k_dense0: flat-part K-split GEMM ----------------
// Grid: 512 WGs = ks(32) x nc(16), XCD-swizzled. WG = 4 waves.
// Stage: xs[k][b] stride 68; one coalesced float4 global read + one b128 LDS write/unit.
__global__ __launch_bounds__(256, 2)
void k_dense0(const float* __restrict__ w0, const float* __restrict__ wsFlatT,
              float* __restrict__ wsPart)
{
    const int blk = blockIdx.x;
    const int lid = (blk & 7)*64 + (blk >> 3);  // XCD-swizzle
    const int ks = lid >> 4;
    const int nc = lid & 15;
    const int n0 = nc*16;
    const int tid  = threadIdx.x;
    const int w    = tid >> 6;
    const int lane = tid & 63;
    const int mg = lane >> 2;
    const int nq = lane & 3;
    const int kbase = ks*196;

    __shared__ float xs[196*68];   // 53312 B; reused as reduce buf

    // stage: unit = (k 0..195, b4 0..15)
    for (int idx = tid; idx < 3136; idx += 256){
        int k  = idx >> 4;
        int b4 = idx & 15;
        float4 v = *(const float4*)(wsFlatT + (kbase + k)*64 + b4*4);
        *(float4*)(&xs[k*68 + b4*4]) = v;
    }
    __syncthreads();

    float acc[4][4];
    #pragma unroll
    for (int i = 0; i < 4; i++)
        #pragma unroll
        for (int c = 0; c < 4; c++) acc[i][c] = 0.f;

    const float* xk = xs + (49*w)*68 + mg*4;
    const float* wpp = w0 + (8 + kbase + 49*w)*256 + n0 + nq*4;
    #pragma unroll 7
    for (int k = 0; k < 49; k++){
        float4 x4 = *(const float4*)(xk + k*68);
        float4 w4 = *(const float4*)(wpp + k*256);
        acc[0][0]=fmaf(x4.x,w4.x,acc[0][0]); acc[0][1]=fmaf(x4.x,w4.y,acc[0][1]);
        acc[0][2]=fmaf(x4.x,w4.z,acc[0][2]); acc[0][3]=fmaf(x4.x,w4.w,acc[0][3]);
        acc[1][0]=fmaf(x4.y,w4.x,acc[1][0]); acc[1][1]=fmaf(x4.y,w4.y,acc[1][1]);
        acc[1][2]=fmaf(x4.y,w4.z,acc[1][2]); acc[1][3]=fmaf(x4.y,w4.w,acc[1][3]);
        acc[2][0]=fmaf(x4.z,w4.x,acc[2][0]); acc[2][1]=fmaf(x4.z,w4.y,acc[2][1]);
        acc[2][2]=fmaf(x4.z,w4.z,acc[2][2]); acc[2][3]=fmaf(x4.z,w4.w,acc[2][3]);
        acc[3][0]=fmaf(x4.w,w4.x,acc[3][0]); acc[3][1]=fmaf(x4.w,w4.y,acc[3][1]);
        acc[3][2]=fmaf(x4.w,w4.z,acc[3][2]); acc[3][3]=fmaf(x4.w,w4.w,acc[3][3]);
    }
    __syncthreads();

    float* red = xs;
    {
        float* rr = red + (w*64 + lane)*17;
        #pragma unroll
        for (int j = 0; j < 16; j++) rr[j] = acc[j>>2][j&3];
    }
    __syncthreads();
    if (tid < 64){
        int mg2 = tid >> 2, nq2 = tid & 3;
        #pragma unroll
        for (int g = 0; g < 4; g++){
            float4 v;
            v.x = red[tid*17+4*g+0] + red[(64+tid)*17+4*g+0] + red[(128+tid)*17+4*g+0] + red[(192+tid)*17+4*g+0];
            v.y = red[tid*17+4*g+1] + red[(64+tid)*17+4*g+1] + red[(128+tid)*17+4*g+1] + red[(192+tid)*17+4*g+1];
            v.z = red[tid*17+4*g+2] + red[(64+tid)*17+4*g+2] + red[(128+tid)*17+4*g+2] + red[(192+tid)*17+4*g+2];
            v.w = red[tid*17+4*g+3] + red[(64+tid)*17+4*g+3] + red[(128+tid)*17+4*g+3] + red[(192+tid)*17+4*g+3];
            int bb = mg2*4 + g;
            *(float4*)(wsPart + (bb*32 + ks)*256 + n0 + nq2*4) = v;
        }
    }
}

// ---------------- launch ----------------
extern "C" void kernel_launch(void* const* d_in, const int* in_sizes, int n_in,
                              void* d_out, int out_size, void* d_ws, size_t ws_size,
                              hipStream_t stream)
{
    (void)in_sizes; (void)n_in; (void)out_size; (void)ws_size;
    const float* action = (const float*)d_in[0];
    const float* state  = (const float*)d_in[1];
    const float* res    = (const float*)d_in[2];
    const float* env    = (const float*)d_in[3];
    const float* origin = (const float*)d_in[4];
    const float* w1  = (const float*)d_in[5];
    const float* b1  = (const float*)d_in[6];
    const float* w2  = (const float*)d_in[7];
    const float* b2  = (const float*)d_in[8];
    const float* w0  = (const float*)d_in[9];
    const float* b0  = (const float*)d_in[10];
    const float* w1d = (const float*)d_in[11];
    const float* b1d = (const float*)d_in[12];
    const float* w2d = (const float*)d_in[13];
    const float* b2d = (const float*)d_in[14];
    float* out = (float*)d_out;

    // ws layout (floats): wsS[1024] | flatT[401408] | part[524288]
    float* wsF     = (float*)d_ws;
    float* wsS     = wsF;
    float* wsFlatT = wsF + 1024;
    float* wsPart  = wsF + 1024 + 401408;

    for (int st = 0; st <= 50; ++st){
        k_tc<<<dim3(512), dim3(256), 0, stream>>>(
            action, state, res, env, origin, w1, b1, w2, b2, w0, b0,
            w1d, b1d, w2d, b2d, wsPart, wsS, wsFlatT, out, st);
        if (st < 50)
            k_dense0<<<dim3(512), dim3(256), 0, stream>>>(w0, wsFlatT, wsPart);
    }
}

// Round 10
// 1811.236 us; speedup vs baseline: 1.1239x; 1.1239x over previous
//
#include <hip/hip_runtime.h>

// B=64, T=50, ROWS=COLS=64, RES=0.03, H_FULL=W_FULL=256
// flat = 14*14*32 = 6272, stored TRANSPOSED: wsFlatT[k][b]
// out: (64,51,6) float32
//
// 151 graph nodes: C0 D0 | (T C D) x49 | T50 FIN
//  k_tail(st): grid 256 = (b,q) x 512 thr. K-split tail:
//              phase A: h1[q*64..+64) = relu(b0 + sum_ks wsPart + W0 rows(s_{st-1},a_{st-1}))
//                       (WG computes FULL h1 for its 64 k-cols; coalesced wsPart reads)
//              phase B: d1part[b][q][col'] = sum_{k in q-range} h1[k]*w1d[k][col']
//                       (scalar w1d reads, lane-coalesced; 64KB/WG, 16MB/step, no redundancy)
//  k_conv(st): prolog (cheap, bit-identical per oct-WG): h2 = relu(sum_q d1part + b1d);
//              ds = W2^T h2 + b2; s_st = s_{st-1} + ds; oct0 writes out+wsS;
//              then params + conv stack -> wsFlatT[k][b]. 512 WGs = (b, oct).
//  k_dense0:   flat-part K-split GEMM -> wsPart[b][32][256] (b-major).
//  k_fin:      prolog-only for row 50.
// State double-buffered by parity: C(st) writes wsS[st&1]; T(st+1)/prolog reads it.

// ---------------- k_tail ----------------
__global__ __launch_bounds__(512)
void k_tail(const float* __restrict__ action, const float* __restrict__ w0,
            const float* __restrict__ b0, const float* __restrict__ w1d,
            const float* __restrict__ wsPart, const float* __restrict__ wsS,
            float* __restrict__ wsD1p, int st)
{
    const int b   = blockIdx.x >> 2;
    const int q   = blockIdx.x & 3;
    const int tid = threadIdx.x;

    __shared__ float hp[512];
    __shared__ float h1l[64];
    __shared__ float dp[512];

    const float* sp = wsS + ((st-1)&1)*512 + b*8;
    const float a0p = action[b*100 + (st-1)*2 + 0];
    const float a1p = action[b*100 + (st-1)*2 + 1];

    // phase A: h1 for cols [q*64, q*64+64). thread = (cl 0..63, ksg 0..7)
    {
        const int cl  = tid & 63;
        const int ksg = tid >> 6;
        const int col = q*64 + cl;
        const float* pp = wsPart + b*8192 + ksg*4*256 + col;
        float h = pp[0] + pp[256] + pp[512] + pp[768];
        if (ksg == 0){
            h += b0[col];
            #pragma unroll
            for (int j = 0; j < 6; j++) h = fmaf(sp[j], w0[j*256 + col], h);
            h = fmaf(a0p, w0[1536 + col], h);
            h = fmaf(a1p, w0[1792 + col], h);
        }
        hp[tid] = h;
    }
    __syncthreads();
    if (tid < 64){
        float s = hp[tid]       + hp[64 + tid]  + hp[128 + tid] + hp[192 + tid]
                + hp[256 + tid] + hp[320 + tid] + hp[384 + tid] + hp[448 + tid];
        h1l[tid] = fmaxf(s, 0.f);
    }
    __syncthreads();

    // phase B: dense1 partial over k in q-range, all 256 cols.
    // thread = (colp 0..255, kh 0..1); w1d reads lane-coalesced.
    {
        const int colp = tid & 255;
        const int kh   = tid >> 8;
        const float* wrow = w1d + (q*64 + kh*32)*256 + colp;
        const float* hh   = h1l + kh*32;
        float d0 = 0.f, d1 = 0.f;
        #pragma unroll 8
        for (int k = 0; k < 32; k += 2){
            d0 = fmaf(hh[k],   wrow[k*256],     d0);
            d1 = fmaf(hh[k+1], wrow[(k+1)*256], d1);
        }
        dp[tid] = d0 + d1;
    }
    __syncthreads();
    if (tid < 256)
        wsD1p[b*1024 + q*256 + tid] = dp[tid] + dp[256 + tid];
}

// ---------------- shared prolog helper (dense2 + state) ----------------
// Executed by 256 threads; needs shared wred[24], sSl[8]. Returns with sSl filled.
__device__ inline void tail_finish(int b, int tid, int st,
                                   const float* __restrict__ wsD1p,
                                   const float* __restrict__ b1d,
                                   const float* __restrict__ w2d,
                                   const float* __restrict__ b2d,
                                   const float* __restrict__ wsS,
                                   float* __restrict__ wred,
                                   float* __restrict__ sSl)
{
    const float* dd = wsD1p + b*1024 + tid;
    float h2 = fmaxf(dd[0] + dd[256] + dd[512] + dd[768] + b1d[tid], 0.f);
    float p[6];
    const float* wr = w2d + tid*6;
    #pragma unroll
    for (int j = 0; j < 6; j++) p[j] = h2 * wr[j];
    #pragma unroll
    for (int off = 32; off > 0; off >>= 1){
        #pragma unroll
        for (int j = 0; j < 6; j++) p[j] += __shfl_down(p[j], off, 64);
    }
    if ((tid & 63) == 0){
        #pragma unroll
        for (int j = 0; j < 6; j++) wred[(tid >> 6)*6 + j] = p[j];
    }
    __syncthreads();
    if (tid < 6){
        float ds = wred[tid] + wred[6+tid] + wred[12+tid] + wred[18+tid] + b2d[tid];
        sSl[tid] = wsS[((st-1)&1)*512 + b*8 + tid] + ds;
    }
    __syncthreads();
}

// ---------------- k_conv ----------------
// Grid: 512 WGs = (b = wg>>3, oct = wg&7); oct owns pool2 rows (2,2,2,2,2,2,1,1).
__global__ __launch_bounds__(256, 2)
void k_conv(const float* __restrict__ action, const float* __restrict__ state,
            const float* __restrict__ res, const float* __restrict__ env,
            const float* __restrict__ origin,
            const float* __restrict__ w1, const float* __restrict__ b1,
            const float* __restrict__ w2, const float* __restrict__ b2,
            const float* __restrict__ b1d, const float* __restrict__ w2d,
            const float* __restrict__ b2d, const float* __restrict__ wsD1p,
            float* __restrict__ wsS, float* __restrict__ wsFlatT,
            float* __restrict__ out, int st)
{
    const int wg  = blockIdx.x;
    const int b   = wg >> 3;
    const int oct = wg & 7;
    const int tid = threadIdx.x;

    __shared__ float w1l[864];
    __shared__ float w2l[4608];
    __shared__ float b2l[32];
    __shared__ float bAl[16];
    __shared__ float sSl[8];
    __shared__ float wred[24];
    __shared__ int   prm[12];
    __shared__ float pool1s[6*31*20];     // 14880 B
    __shared__ unsigned char inl[14*64];  // 896 B

    // conv weight staging issued first (long latency-to-use)
    for (int i = tid; i < 216; i += 256)
        *(float4*)&w1l[i*4] = *(const float4*)(w1 + i*4);
    for (int i = tid; i < 1152; i += 256)
        *(float4*)&w2l[i*4] = *(const float4*)(w2 + i*4);
    if (tid < 32) b2l[tid] = b2[tid];

    // prolog: finish tail -> s_st (bit-identical across octs; tiny)
    if (st == 0){
        if (tid < 6) sSl[tid] = state[b*306 + tid];
        __syncthreads();
    } else {
        tail_finish(b, tid, st, wsD1p, b1d, w2d, b2d, wsS, wred, sSl);
    }

    if (oct == 0 && tid < 6){
        out[b*306 + st*6 + tid] = sSl[tid];
        wsS[(st & 1)*512 + b*8 + tid] = sSl[tid];
    }

    // params + conv constants
    if (tid == 0){
        float org0 = origin[2*b], org1 = origin[2*b+1];
        int ccol = (int)(sSl[4] / 0.03f + org1);   // trunc == astype(int32)
        int crow = (int)(sSl[5] / 0.03f + org0);
        float res0 = res[b*50];
        float lo0 = org0 - (float)crow + 32.0f;
        float lo1 = org1 - (float)ccol + 32.0f;
        prm[0] = crow; prm[1] = ccol;
        #pragma unroll
        for (int p = 0; p < 3; p++){
            int rr = (int)(sSl[2*p+1]/res0 + lo0);
            int cc = (int)(sSl[2*p  ]/res0 + lo1);
            prm[2+p] = rr; prm[5+p] = cc;
            prm[8+p] = (rr>=0 && rr<64 && cc>=0 && cc<64) ? 1 : 0;
        }
    }
    if (tid < 16){
        float s4 = 0.f, s5 = 0.f;
        #pragma unroll
        for (int k = 0; k < 9; k++){
            s4 += w1[(k*6 + 4)*16 + tid];
            s5 += w1[(k*6 + 5)*16 + tid];
        }
        float a0 = action[b*100 + st*2 + 0];
        float a1 = action[b*100 + st*2 + 1];
        bAl[tid] = b1[tid] + a0*s4 + a1*s5;
    }
    __syncthreads();

    // conv geometry for this oct (pool2 rows 2,2,2,2,2,2,1,1)
    const int p2lo = (oct < 6) ? 2*oct : 12 + (oct - 6);
    const int p2n  = (oct < 6) ? 2 : 1;
    const int p1n  = 2*p2n + 2;      // 6 or 4
    const int p1lo = 2*p2lo;
    const int ilo  = 4*p2lo;
    const int inn  = 2*p1n + 2;      // 14 or 10

    // window gather
    {
        const int crow = prm[0], ccol = prm[1];
        for (int idx = tid; idx < inn*64; idx += 256){
            int i = idx >> 6, j = idx & 63;
            int r = crow - 32 + ilo + i;
            int c = ccol - 32 + j;
            float v = (r>=0 && r<256 && c>=0 && c<256) ? env[b*65536 + (r<<8) + c] : 0.f;
            inl[idx] = (unsigned char)v;
        }
    }
    __syncthreads();

    // conv1 + pool1
    {
        int pr[3], pc[3], pvld[3];
        #pragma unroll
        for (int p = 0; p < 3; p++){ pr[p]=prm[2+p]; pc[p]=prm[5+p]; pvld[p]=prm[8+p]; }

        for (int u = tid; u < p1n*31; u += 256){
            int pl = u / 31;
            int j  = u - pl*31;
            float l[4][4];
            #pragma unroll
            for (int dy = 0; dy < 4; dy++)
                #pragma unroll
                for (int dx = 0; dx < 4; dx++)
                    l[dy][dx] = (float)inl[(2*pl + dy)*64 + 2*j + dx];

            float m[16];
            #pragma unroll
            for (int o = 0; o < 16; o++) m[o] = 0.f;   // relu>=0

            #pragma unroll
            for (int dy = 0; dy < 2; dy++){
                #pragma unroll
                for (int dx = 0; dx < 2; dx++){
                    int rg = 2*(p1lo + pl) + dy;
                    int cg = 2*j + dx;
                    bool pf[3]; int pidx[3];
                    #pragma unroll
                    for (int p = 0; p < 3; p++){
                        int kr = pr[p] - rg, kc = pc[p] - cg;
                        pf[p] = pvld[p] && kr >= 0 && kr < 3 && kc >= 0 && kc < 3;
                        pidx[p] = pf[p] ? ((kr*3 + kc)*6 + p)*16 : 0;
                    }
                    #pragma unroll
                    for (int o = 0; o < 16; o++){
                        float v = bAl[o];
                        #pragma unroll
                        for (int kr = 0; kr < 3; kr++)
                            #pragma unroll
                            for (int kc = 0; kc < 3; kc++)
                                v = fmaf(l[dy+kr][dx+kc], w1l[((kr*3 + kc)*6 + 3)*16 + o], v);
                        if (pf[0]) v += w1l[pidx[0] + o];
                        if (pf[1]) v += w1l[pidx[1] + o];
                        if (pf[2]) v += w1l[pidx[2] + o];
                        v = fmaxf(v, 0.f);
                        m[o] = fmaxf(m[o], v);
                    }
                }
            }
            float* pd = &pool1s[(pl*31 + j)*20];
            *(float4*)(pd     ) = make_float4(m[0],  m[1],  m[2],  m[3]);
            *(float4*)(pd + 4 ) = make_float4(m[4],  m[5],  m[6],  m[7]);
            *(float4*)(pd + 8 ) = make_float4(m[8],  m[9],  m[10], m[11]);
            *(float4*)(pd + 12) = make_float4(m[12], m[13], m[14], m[15]);
        }
    }
    __syncthreads();

    // conv2 + pool2 -> wsFlatT[k][b] (transposed scatter stores)
    for (int u = tid; u < p2n*14*8; u += 256){
        int pi  = u / 112;
        int rem = u - pi*112;
        int jj  = rem >> 3;
        int oq  = rem & 7;
        int o0  = oq*4;

        float acc[4][4];
        #pragma unroll
        for (int ps = 0; ps < 4; ps++)
            #pragma unroll
            for (int c = 0; c < 4; c++) acc[ps][c] = 0.f;

        #pragma unroll 1
        for (int t9 = 0; t9 < 9; t9++){
            int kr = t9 / 3, kc = t9 - 3*(t9/3);
            const float* pb = &pool1s[((2*pi + kr)*31 + (2*jj + kc))*20];
            const float* wb = &w2l[(kr*3 + kc)*512 + o0];
            #pragma unroll
            for (int kib = 0; kib < 4; kib++){
                float4 q00 = *(const float4*)(pb + kib*4);
                float4 q01 = *(const float4*)(pb + 20 + kib*4);
                float4 q10 = *(const float4*)(pb + 620 + kib*4);
                float4 q11 = *(const float4*)(pb + 640 + kib*4);
                float pq[4][4] = {
                    {q00.x, q00.y, q00.z, q00.w},
                    {q01.x, q01.y, q01.z, q01.w},
                    {q10.x, q10.y, q10.z, q10.w},
                    {q11.x, q11.y, q11.z, q11.w}};
                #pragma unroll
                for (int kk = 0; kk < 4; kk++){
                    float4 wv = *(const float4*)(wb + (kib*4 + kk)*32);
                    #pragma unroll
                    for (int ps = 0; ps < 4; ps++){
                        float pvv = pq[ps][kk];
                        acc[ps][0] = fmaf(pvv, wv.x, acc[ps][0]);
                        acc[ps][1] = fmaf(pvv, wv.y, acc[ps][1]);
                        acc[ps][2] = fmaf(pvv, wv.z, acc[ps][2]);
                        acc[ps][3] = fmaf(pvv, wv.w, acc[ps][3]);
                    }
                }
            }
        }
        int kb = ((p2lo + pi)*14 + jj)*32 + o0;
        #pragma unroll
        for (int c = 0; c < 4; c++){
            float bb = b2l[o0 + c];
            float v0 = fmaxf(acc[0][c] + bb, 0.f);
            float v1 = fmaxf(acc[1][c] + bb, 0.f);
            float v2 = fmaxf(acc[2][c] + bb, 0.f);
            float v3 = fmaxf(acc[3][c] + bb, 0.f);
            wsFlatT[(kb + c)*64 + b] = fmaxf(fmaxf(v0, v1), fmaxf(v2, v3));
        }
    }
}

// ---------------- k_dense0: flat-part K-split GEMM ----------------
// Grid: 512 WGs = ks(32) x nc(16), XCD-swizzled. WG = 4 waves.
// Stage: xs[k][b] stride 68; one coalesced float4 global read + one b128 LDS write/unit.
__global__ __launch_bounds__(256, 2)
void k_dense0(const float* __restrict__ w0, const float* __restrict__ wsFlatT,
              float* __restrict__ wsPart)
{
    const int blk = blockIdx.x;
    const int lid = (blk & 7)*64 + (blk >> 3);  // XCD-swizzle
    const int ks = lid >> 4;
    const int nc = lid & 15;
    const int n0 = nc*16;
    const int tid  = threadIdx.x;
    const int w    = tid >> 6;
    const int lane = tid & 63;
    const int mg = lane >> 2;
    const int nq = lane & 3;
    const int kbase = ks*196;

    __shared__ float xs[196*68];   // 53312 B; reused as reduce buf

    for (int idx = tid; idx < 3136; idx += 256){
        int k  = idx >> 4;
        int b4 = idx & 15;
        float4 v = *(const float4*)(wsFlatT + (kbase + k)*64 + b4*4);
        *(float4*)(&xs[k*68 + b4*4]) = v;
    }
    __syncthreads();

    float acc[4][4];
    #pragma unroll
    for (int i = 0; i < 4; i++)
        #pragma unroll
        for (int c = 0; c < 4; c++) acc[i][c] = 0.f;

    const float* xk = xs + (49*w)*68 + mg*4;
    const float* wpp = w0 + (8 + kbase + 49*w)*256 + n0 + nq*4;
    #pragma unroll 7
    for (int k = 0; k < 49; k++){
        float4 x4 = *(const float4*)(xk + k*68);
        float4 w4 = *(const float4*)(wpp + k*256);
        acc[0][0]=fmaf(x4.x,w4.x,acc[0][0]); acc[0][1]=fmaf(x4.x,w4.y,acc[0][1]);
        acc[0][2]=fmaf(x4.x,w4.z,acc[0][2]); acc[0][3]=fmaf(x4.x,w4.w,acc[0][3]);
        acc[1][0]=fmaf(x4.y,w4.x,acc[1][0]); acc[1][1]=fmaf(x4.y,w4.y,acc[1][1]);
        acc[1][2]=fmaf(x4.y,w4.z,acc[1][2]); acc[1][3]=fmaf(x4.y,w4.w,acc[1][3]);
        acc[2][0]=fmaf(x4.z,w4.x,acc[2][0]); acc[2][1]=fmaf(x4.z,w4.y,acc[2][1]);
        acc[2][2]=fmaf(x4.z,w4.z,acc[2][2]); acc[2][3]=fmaf(x4.z,w4.w,acc[2][3]);
        acc[3][0]=fmaf(x4.w,w4.x,acc[3][0]); acc[3][1]=fmaf(x4.w,w4.y,acc[3][1]);
        acc[3][2]=fmaf(x4.w,w4.z,acc[3][2]); acc[3][3]=fmaf(x4.w,w4.w,acc[3][3]);
    }
    __syncthreads();

    float* red = xs;
    {
        float* rr = red + (w*64 + lane)*17;
        #pragma unroll
        for (int j = 0; j < 16; j++) rr[j] = acc[j>>2][j&3];
    }
    __syncthreads();
    if (tid < 64){
        int mg2 = tid >> 2, nq2 = tid & 3;
        #pragma unroll
        for (int g = 0; g < 4; g++){
            float4 v;
            v.x = red[tid*17+4*g+0] + red[(64+tid)*17+4*g+0] + red[(128+tid)*17+4*g+0] + red[(192+tid)*17+4*g+0];
            v.y = red[tid*17+4*g+1] + red[(64+tid)*17+4*g+1] + red[(128+tid)*17+4*g+1] + red[(192+tid)*17+4*g+1];
            v.z = red[tid*17+4*g+2] + red[(64+tid)*17+4*g+2] + red[(128+tid)*17+4*g+2] + red[(192+tid)*17+4*g+2];
            v.w = red[tid*17+4*g+3] + red[(64+tid)*17+4*g+3] + red[(128+tid)*17+4*g+3] + red[(192+tid)*17+4*g+3];
            int bb = mg2*4 + g;
            *(float4*)(wsPart + (bb*32 + ks)*256 + n0 + nq2*4) = v;
        }
    }
}

// ---------------- k_fin: final state row 50 ----------------
__global__ __launch_bounds__(256)
void k_fin(const float* __restrict__ b1d, const float* __restrict__ w2d,
           const float* __restrict__ b2d, const float* __restrict__ wsD1p,
           const float* __restrict__ wsS, float* __restrict__ out)
{
    const int b = blockIdx.x;
    const int tid = threadIdx.x;
    __shared__ float wred[24];
    __shared__ float sSl[8];
    tail_finish(b, tid, 50, wsD1p, b1d, w2d, b2d, wsS, wred, sSl);
    if (tid < 6) out[b*306 + 300 + tid] = sSl[tid];
}

// ---------------- launch ----------------
extern "C" void kernel_launch(void* const* d_in, const int* in_sizes, int n_in,
                              void* d_out, int out_size, void* d_ws, size_t ws_size,
                              hipStream_t stream)
{
    (void)in_sizes; (void)n_in; (void)out_size; (void)ws_size;
    const float* action = (const float*)d_in[0];
    const float* state  = (const float*)d_in[1];
    const float* res    = (const float*)d_in[2];
    const float* env    = (const float*)d_in[3];
    const float* origin = (const float*)d_in[4];
    const float* w1  = (const float*)d_in[5];
    const float* b1  = (const float*)d_in[6];
    const float* w2  = (const float*)d_in[7];
    const float* b2  = (const float*)d_in[8];
    const float* w0  = (const float*)d_in[9];
    const float* b0  = (const float*)d_in[10];
    const float* w1d = (const float*)d_in[11];
    const float* b1d = (const float*)d_in[12];
    const float* w2d = (const float*)d_in[13];
    const float* b2d = (const float*)d_in[14];
    float* out = (float*)d_out;

    // ws layout (floats): wsS[1024] | wsD1p[65536] | flatT[401408] | part[524288]
    float* wsF     = (float*)d_ws;
    float* wsS     = wsF;
    float* wsD1p   = wsF + 1024;
    float* wsFlatT = wsF + 1024 + 65536;
    float* wsPart  = wsF + 1024 + 65536 + 401408;

    k_conv<<<dim3(512), dim3(256), 0, stream>>>(
        action, state, res, env, origin, w1, b1, w2, b2,
        b1d, w2d, b2d, wsD1p, wsS, wsFlatT, out, 0);
    k_dense0<<<dim3(512), dim3(256), 0, stream>>>(w0, wsFlatT, wsPart);

    for (int st = 1; st < 50; ++st){
        k_tail<<<dim3(256), dim3(512), 0, stream>>>(
            action, w0, b0, w1d, wsPart, wsS, wsD1p, st);
        k_conv<<<dim3(512), dim3(256), 0, stream>>>(
            action, state, res, env, origin, w1, b1, w2, b2,
            b1d, w2d, b2d, wsD1p, wsS, wsFlatT, out, st);
        k_dense0<<<dim3(512), dim3(256), 0, stream>>>(w0, wsFlatT, wsPart);
    }
    k_tail<<<dim3(256), dim3(512), 0, stream>>>(
        action, w0, b0, w1d, wsPart, wsS, wsD1p, 50);
    k_fin<<<dim3(64), dim3(256), 0, stream>>>(b1d, w2d, b2d, wsD1p, wsS, out);
}